// Round 4
// baseline (226.457 us; speedup 1.0000x reference)
//
#include <hip/hip_runtime.h>
#include <cstddef>
#include <cstdint>

typedef unsigned short u16;
typedef unsigned int   u32;

#define S_LEN  1024
#define NHEAD  16
#define HDIM   64
#define DMODEL 1024
#define NORMSC 0.125f
#define BIGC   1000000.0f
#define LOG2E  1.44269504088896f
#define SC2    (0.125f * 1.44269504088896f)

typedef __bf16 bf16x8 __attribute__((ext_vector_type(8)));
typedef float  f32x4  __attribute__((ext_vector_type(4)));

#define MFMA16(a, b, c) __builtin_amdgcn_mfma_f32_16x16x32_bf16((a), (b), (c), 0, 0, 0)

__device__ __forceinline__ u16 f2bf(float f) {
    u32 u = __float_as_uint(f);
    u32 r = (u + 0x7fffu + ((u >> 16) & 1u)) >> 16;
    return (u16)r;
}
__device__ __forceinline__ float bf2f(u32 v) {
    return __uint_as_float(v << 16);
}
__device__ __forceinline__ float4 unp4(uint2 u) {
    float4 f;
    f.x = bf2f(u.x & 0xffffu); f.y = bf2f(u.x >> 16);
    f.z = bf2f(u.y & 0xffffu); f.w = bf2f(u.y >> 16);
    return f;
}
__device__ __forceinline__ void async16(const void* g, void* l) {
    __builtin_amdgcn_global_load_lds(
        (__attribute__((address_space(1))) void*)(g),
        (__attribute__((address_space(3))) void*)(l), 16, 0, 0);
}

// ---------------- prep_all: fp32->bf16 conversions + weight transposes ----------------
__global__ __launch_bounds__(256) void prep_all(
    const float* q, const float* k, const float* v, const float* pos,
    const float* qw, const float* kw, const float* vw, const float* pw, const float* rk,
    u16* qbf, u16* kbf, u16* vbf, u16* posb,
    u16* qwT, u16* kwT, u16* vwT, u16* pwT, u16* WrT)
{
    __shared__ float tb[32][33];
    const int bid = blockIdx.x, tid = threadIdx.x;
    if (bid < 7168) {
        const float* s; u16* d; int base;
        if (bid < 2048)      { s = q;   d = qbf;  base = bid; }
        else if (bid < 4096) { s = k;   d = kbf;  base = bid - 2048; }
        else if (bid < 6144) { s = v;   d = vbf;  base = bid - 4096; }
        else                 { s = pos; d = posb; base = bid - 6144; }
        const int i = base * 1024 + tid * 4;
        const float4 val = *(const float4*)&s[i];
        uint2 o;
        o.x = (u32)f2bf(val.x) | ((u32)f2bf(val.y) << 16);
        o.y = (u32)f2bf(val.z) | ((u32)f2bf(val.w) << 16);
        *(uint2*)&d[i] = o;
        return;
    }
    const int t = bid - 7168;
    const float* in; u16* out; int ild, r0, c0;
    if (t < 4096) {
        const int ts = t & 1023;
        if (t < 1024)      { in = qw; out = qwT; }
        else if (t < 2048) { in = kw; out = kwT; }
        else if (t < 3072) { in = vw; out = vwT; }
        else               { in = pw; out = pwT; }
        ild = 1024;
        r0 = (ts >> 5) * 32; c0 = (ts & 31) * 32;
    } else {
        const int ts = t - 4096;
        const int n = ts >> 6, tt = ts & 63;
        in = rk + (size_t)n * 65536; out = WrT + (size_t)n * 65536;
        ild = 64;
        r0 = (tt >> 1) * 32; c0 = (tt & 1) * 32;
    }
    const int tx = tid & 31, ty = tid >> 5;
    for (int i = ty; i < 32; i += 8)
        tb[i][tx] = in[(size_t)(r0 + i) * ild + c0 + tx];
    __syncthreads();
    for (int i = ty; i < 32; i += 8)
        out[(size_t)(c0 + i) * 1024 + r0 + tx] = f2bf(tb[tx][i]);
}

// ---------------- MFMA bf16 GEMM, bf16 row-major partial output ----------------
// C(Mx1024 bf16) = A(Mx1024) @ Bt(1024x1024)^T over k in [k0, k0+klen)
struct GJ { const u16* A; const u16* Bt; u16* C; int M; int k0; int klen; };

__global__ __launch_bounds__(256) void gemm_p(
    GJ j0, GJ j1, GJ j2, GJ j3, GJ j4, GJ j5, GJ j6, GJ j7)
{
    GJ g;
    switch (blockIdx.z) {
        case 0: g = j0; break; case 1: g = j1; break;
        case 2: g = j2; break; case 3: g = j3; break;
        case 4: g = j4; break; case 5: g = j5; break;
        case 6: g = j6; break; default: g = j7;
    }
    const int bm = blockIdx.y * 128;
    if (bm >= g.M) return;
    const int bn = blockIdx.x * 128;
    __shared__ u16 As[4096];  // 128 rows x 32 k, 8KB
    __shared__ u16 Bs[4096];
    const int tid = threadIdx.x;
    const int w = tid >> 6, lane = tid & 63;
    const int wm = (w >> 1) * 64, wn = (w & 1) * 64;
    const int l15 = lane & 15, l16 = lane >> 4;
    f32x4 acc[4][4] = {};
    const char* Ab = (const char*)g.A;
    const char* Bb = (const char*)g.Bt;
    const int kend = g.k0 + g.klen;
    for (int k0 = g.k0; k0 < kend; k0 += 32) {
        __syncthreads();
#pragma unroll
        for (int i = 0; i < 2; ++i) {
            const int m = (i * 4 + w) * 1024 + lane * 16;
            const int r = m >> 6, cb = m & 63;
            async16(Ab + ((size_t)(bm + r) * 1024 + k0) * 2 + cb, (char*)As + m);
            async16(Bb + ((size_t)(bn + r) * 1024 + k0) * 2 + cb, (char*)Bs + m);
        }
        __syncthreads();
        bf16x8 af[4], bfr[4];
#pragma unroll
        for (int i = 0; i < 4; ++i)
            af[i] = *(const bf16x8*)&As[(wm + i * 16 + l15) * 32 + l16 * 8];
#pragma unroll
        for (int j = 0; j < 4; ++j)
            bfr[j] = *(const bf16x8*)&Bs[(wn + j * 16 + l15) * 32 + l16 * 8];
#pragma unroll
        for (int i = 0; i < 4; ++i)
#pragma unroll
            for (int j = 0; j < 4; ++j)
                acc[i][j] = MFMA16(af[i], bfr[j], acc[i][j]);
    }
#pragma unroll
    for (int i = 0; i < 4; ++i)
#pragma unroll
        for (int j = 0; j < 4; ++j) {
            const int c = bn + wn + j * 16 + l15;
#pragma unroll
            for (int rg = 0; rg < 4; ++rg) {
                const int m = bm + wm + i * 16 + l16 * 4 + rg;
                g.C[(size_t)m * 1024 + c] = f2bf(acc[i][j][rg]);
            }
        }
}

// ---------------- prep2: combine split-K partials into keff/cc, vT, qh ----------------
// [0,2048): keff = bf16(pk0+pk1+kb + pr0+pr1), cc = LOG2E*(NORM*(rw.kv+rr.rv) - BIG*mask)
// [2048,4096): vT transpose from (pv0+pv1+vb)
// [4096,6144): qhb = bf16(pq0+pq1) scattered to (b,n,l,h)
__global__ __launch_bounds__(256) void prep2(
    const u16* pk0, const u16* pk1, const u16* pr0, const u16* pr1,
    const u16* pv0, const u16* pv1, const u16* pq0, const u16* pq1,
    const float* kbi, const float* vbi, const float* rwb, const float* rrb,
    const int* mask, u16* keff, float* cc, u16* vT, u16* qhb)
{
    __shared__ float tb[32][33];
    const int bid = blockIdx.x, tid = threadIdx.x;
    if (bid < 2048) {
        const int t = bid * 256 + tid;
        const int row = t >> 4, li = t & 15;
        const int n = (row >> 10) & 15, kk = row & 1023, b = row >> 14;
        const size_t mi = ((size_t)(b * 1024 + kk)) * 1024 + n * 64 + li * 4;
        const size_t pi = ((size_t)kk) * 1024 + n * 64 + li * 4;
        const float4 k0v = unp4(*(const uint2*)&pk0[mi]);
        const float4 k1v = unp4(*(const uint2*)&pk1[mi]);
        const float4 r0v = unp4(*(const uint2*)&pr0[pi]);
        const float4 r1v = unp4(*(const uint2*)&pr1[pi]);
        const float4 kb4 = *(const float4*)&kbi[n * 64 + li * 4];
        float4 kv, rv;
        kv.x = k0v.x + k1v.x + kb4.x; kv.y = k0v.y + k1v.y + kb4.y;
        kv.z = k0v.z + k1v.z + kb4.z; kv.w = k0v.w + k1v.w + kb4.w;
        rv.x = r0v.x + r1v.x; rv.y = r0v.y + r1v.y;
        rv.z = r0v.z + r1v.z; rv.w = r0v.w + r1v.w;
        const float4 w1 = *(const float4*)&rwb[n * 64 + li * 4];
        const float4 w2 = *(const float4*)&rrb[n * 64 + li * 4];
        float s = w1.x * kv.x + w1.y * kv.y + w1.z * kv.z + w1.w * kv.w
                + w2.x * rv.x + w2.y * rv.y + w2.z * rv.z + w2.w * rv.w;
        uint2 o;
        o.x = (u32)f2bf(kv.x + rv.x) | ((u32)f2bf(kv.y + rv.y) << 16);
        o.y = (u32)f2bf(kv.z + rv.z) | ((u32)f2bf(kv.w + rv.w) << 16);
        *(uint2*)&keff[(size_t)row * 64 + li * 4] = o;
#pragma unroll
        for (int m = 1; m < 16; m <<= 1) s += __shfl_xor(s, m);
        if (li == 0)
            cc[row] = LOG2E * (NORMSC * s - BIGC * (float)mask[b * 1024 + kk]);
        return;
    }
    if (bid < 4096) {
        const int t = bid - 2048;
        const int head = t >> 6, tt = t & 63;
        const int b = head >> 4, n = head & 15;
        const int r0 = (tt >> 1) * 32, c0 = (tt & 1) * 32;
        const int tx = tid & 31, ty = tid >> 5;
        const float vb = vbi[n * 64 + c0 + tx];
        for (int i = ty; i < 32; i += 8) {
            const size_t idx = ((size_t)(b * 1024 + r0 + i)) * 1024 + n * 64 + c0 + tx;
            tb[i][tx] = bf2f(pv0[idx]) + bf2f(pv1[idx]) + vb;
        }
        __syncthreads();
        u16* out = vT + (size_t)head * 65536;
        for (int i = ty; i < 32; i += 8)
            out[(size_t)(c0 + i) * 1024 + r0 + tx] = f2bf(tb[tx][i]);
        return;
    }
    const int t = bid - 4096;
    const int e = t * 1024 + tid * 4;
    const int m = e >> 10, c = e & 1023;
    const float4 a = unp4(*(const uint2*)&pq0[e]);
    const float4 b4 = unp4(*(const uint2*)&pq1[e]);
    uint2 o;
    o.x = (u32)f2bf(a.x + b4.x) | ((u32)f2bf(a.y + b4.y) << 16);
    o.y = (u32)f2bf(a.z + b4.z) | ((u32)f2bf(a.w + b4.w) << 16);
    const int b2 = m >> 10, l = m & 1023, n = c >> 6, h = c & 63;
    *(uint2*)&qhb[(((size_t)(b2 * NHEAD + n)) * 1024 + l) * 64 + h] = o;
}

// ---------------- MFMA flash attention, split-K over key halves ----------------
// 1024 blocks x 256 thr: bid = ks*512 + head*16 + rowtile; 64 q-rows/block; 4 chunks of 128 keys.
// Rotation-swizzled LDS; no online max (scores bounded; masked -> exp2(-1.44e6)=0).
// Writes unnormalized O partial (fp32) + row sums.
__global__ __launch_bounds__(256) void attn_mfma(
    const u16* qb, const u16* kb, const u16* vtb, const float* ccomb,
    float* o0, float* o1, float* lsb0, float* lsb1)
{
    __shared__ u16   Ks[8192];      // 128 keys x 64 h rotated, 16KB
    __shared__ u16   Vs[8192];      // 64 h x 128 keys rotated, 16KB
    __shared__ __bf16 Ps[4][1024];  // per-wave 16x64 P rotated, 8KB
    const int tid = threadIdx.x;
    const int w = tid >> 6, lane = tid & 63;
    const int l15 = lane & 15, l16 = lane >> 4;
    const int ks = blockIdx.x >> 9;
    const int r = blockIdx.x & 511;
    const int head = r >> 4;
    const int q0 = (r & 15) * 64;
    const int b = head >> 4, n = head & 15;
    const size_t hoff = (size_t)head * 65536;
    const u16* qh = qb + hoff;
    const char* khc = (const char*)(kb + hoff);
    const char* vtc = (const char*)(vtb + hoff);
    const float* cc = ccomb + head * 1024;
    float* Op = ks ? o1 : o0;
    float* ls = ks ? lsb1 : lsb0;
    __bf16* Pw = Ps[w];

    bf16x8 qf[2];
    {
        const size_t rb = ((size_t)(q0 + w * 16 + l15)) * 64 + l16 * 8;
        qf[0] = *(const bf16x8*)&qh[rb];
        qf[1] = *(const bf16x8*)&qh[rb + 32];
    }
    f32x4 Oacc[4] = {};
    float lsum[4] = {};

    for (int kc = ks * 4; kc < ks * 4 + 4; ++kc) {
        __syncthreads();
#pragma unroll
        for (int i = 0; i < 4; ++i) {
            const int m = (i * 4 + w) * 1024 + lane * 16;
            const int kr = m >> 7, kcc = (m >> 4) & 7;
            async16(khc + kc * 16384 + kr * 128 + (((kcc + kr) & 7) << 4), (char*)Ks + m);
            const int vr = m >> 8, vc = (m >> 4) & 15;
            async16(vtc + (size_t)vr * 2048 + kc * 256 + (((vc + vr) & 15) << 4), (char*)Vs + m);
        }
        __syncthreads();

        f32x4 sc[8];
#pragma unroll
        for (int j = 0; j < 8; ++j) {
            const int rk2 = j * 16 + l15;
            const int base = rk2 * 64;
            f32x4 a = {0.f, 0.f, 0.f, 0.f};
            a = MFMA16(qf[0], *(const bf16x8*)&Ks[base + (((l16 - rk2) & 7) << 3)], a);
            a = MFMA16(qf[1], *(const bf16x8*)&Ks[base + (((l16 + 4 - rk2) & 7) << 3)], a);
            const float cadd = cc[kc * 128 + j * 16 + l15];
            sc[j] = a * SC2 + cadd;
        }
        // two half-chunks of 64 keys: P write (16x64) then PV
#pragma unroll
        for (int h2 = 0; h2 < 2; ++h2) {
#pragma unroll
            for (int j2 = 0; j2 < 4; ++j2) {
                const int j = h2 * 4 + j2;
                const int cg = j2 * 2 + (l15 >> 3);
#pragma unroll
                for (int rg = 0; rg < 4; ++rg) {
                    const float p = exp2f(sc[j][rg]);
                    lsum[rg] += p;
                    const int row = l16 * 4 + rg;
                    Pw[row * 64 + (((cg - row) & 7) << 3) + (l15 & 7)] = (__bf16)p;
                }
            }
            bf16x8 pf[2];
#pragma unroll
            for (int f = 0; f < 2; ++f)
                pf[f] = *(const bf16x8*)&Pw[l15 * 64 + (((f * 4 + l16 - l15) & 7) << 3)];
#pragma unroll
            for (int t4 = 0; t4 < 4; ++t4) {
#pragma unroll
                for (int f = 0; f < 2; ++f) {
                    const int vr = t4 * 16 + l15;
                    const int ch = h2 * 8 + f * 4 + l16;
                    const bf16x8 vf = *(const bf16x8*)&Vs[vr * 128 + (((ch - vr) & 15) << 3)];
                    Oacc[t4] = MFMA16(pf[f], vf, Oacc[t4]);
                }
            }
        }
    }
    // write unnormalized O partial + row sums
#pragma unroll
    for (int t4 = 0; t4 < 4; ++t4)
#pragma unroll
        for (int rg = 0; rg < 4; ++rg) {
            const int srow = q0 + w * 16 + l16 * 4 + rg;
            const int col = n * 64 + t4 * 16 + l15;
            Op[((size_t)b * 1024 + srow) * 1024 + col] = Oacc[t4][rg];
        }
    float4 s4;
#pragma unroll
    for (int rg = 0; rg < 4; ++rg) {
        float s = lsum[rg];
#pragma unroll
        for (int m = 1; m < 16; m <<= 1) s += __shfl_xor(s, m);
        ((float*)&s4)[rg] = s;
    }
    if (l15 == 0)
        *(float4*)&ls[head * 1024 + q0 + w * 16 + l16 * 4] = s4;
}

// ---------------- combine O partials -> normalized bf16 ----------------
__global__ __launch_bounds__(256) void comb_o(
    const float* o0, const float* o1, const float* ls0, const float* ls1, u16* Obf)
{
    const int i = (blockIdx.x * 256 + threadIdx.x) * 4;
    const int row = i >> 10, col = i & 1023;
    const int b = row >> 10, s = row & 1023, n = col >> 6;
    const int head = b * 16 + n;
    const float inv = 1.0f / (ls0[head * 1024 + s] + ls1[head * 1024 + s]);
    const float4 a = *(const float4*)&o0[i];
    const float4 c = *(const float4*)&o1[i];
    uint2 o;
    o.x = (u32)f2bf((a.x + c.x) * inv) | ((u32)f2bf((a.y + c.y) * inv) << 16);
    o.y = (u32)f2bf((a.z + c.z) * inv) | ((u32)f2bf((a.w + c.w) * inv) << 16);
    *(uint2*)&Obf[i] = o;
}

// ---------------- layernorm: out = LN(po0+po1+po2+po3 + post_b + resid) ----------------
__global__ __launch_bounds__(256) void ln_kernel(
    const u16* __restrict__ p0, const u16* __restrict__ p1,
    const u16* __restrict__ p2, const u16* __restrict__ p3,
    const float* __restrict__ resid, const float* __restrict__ pb,
    const float* __restrict__ g, const float* __restrict__ bb,
    float* __restrict__ out)
{
    const int row = blockIdx.x;
    const int tid = threadIdx.x;
    const size_t i = (size_t)row * DMODEL + tid * 4;
    const float4 a0 = unp4(*(const uint2*)&p0[i]);
    const float4 a1 = unp4(*(const uint2*)&p1[i]);
    const float4 a2 = unp4(*(const uint2*)&p2[i]);
    const float4 a3 = unp4(*(const uint2*)&p3[i]);
    const float4 rr = *(const float4*)&resid[i];
    const float4 pv = *(const float4*)&pb[tid * 4];
    float4 v;
    v.x = a0.x + a1.x + a2.x + a3.x + rr.x + pv.x;
    v.y = a0.y + a1.y + a2.y + a3.y + rr.y + pv.y;
    v.z = a0.z + a1.z + a2.z + a3.z + rr.z + pv.z;
    v.w = a0.w + a1.w + a2.w + a3.w + rr.w + pv.w;
    float s1 = v.x + v.y + v.z + v.w;
    float s2 = v.x * v.x + v.y * v.y + v.z * v.z + v.w * v.w;
#pragma unroll
    for (int off = 32; off; off >>= 1) {
        s1 += __shfl_down(s1, off);
        s2 += __shfl_down(s2, off);
    }
    __shared__ float rb[8];
    if ((tid & 63) == 0) { rb[tid >> 6] = s1; rb[4 + (tid >> 6)] = s2; }
    __syncthreads();
    if (tid == 0) {
        rb[0] = rb[0] + rb[1] + rb[2] + rb[3];
        rb[4] = rb[4] + rb[5] + rb[6] + rb[7];
    }
    __syncthreads();
    s1 = rb[0]; s2 = rb[4];
    const float mu = s1 * (1.0f / DMODEL);
    const float var = s2 * (1.0f / DMODEL) - mu * mu;
    const float rstd = rsqrtf(var + 1e-5f);
    const float4 gv = *(const float4*)&g[tid * 4];
    const float4 bv = *(const float4*)&bb[tid * 4];
    float4 o;
    o.x = (v.x - mu) * rstd * gv.x + bv.x;
    o.y = (v.y - mu) * rstd * gv.y + bv.y;
    o.z = (v.z - mu) * rstd * gv.z + bv.z;
    o.w = (v.w - mu) * rstd * gv.w + bv.w;
    *(float4*)&out[i] = o;
}

extern "C" void kernel_launch(void* const* d_in, const int* in_sizes, int n_in,
                              void* d_out, int out_size, void* d_ws, size_t ws_size,
                              hipStream_t stream)
{
    (void)in_sizes; (void)n_in; (void)out_size; (void)ws_size;
    const float* q   = (const float*)d_in[0];
    const float* k   = (const float*)d_in[1];
    const float* v   = (const float*)d_in[2];
    const float* pos = (const float*)d_in[3];
    const int*   msk = (const int*)d_in[4];
    const float* qw  = (const float*)d_in[5];
    const float* kw  = (const float*)d_in[6];
    const float* kbi = (const float*)d_in[7];
    const float* vw  = (const float*)d_in[8];
    const float* vbi = (const float*)d_in[9];
    const float* rwb = (const float*)d_in[10];
    const float* rrb = (const float*)d_in[11];
    const float* rk  = (const float*)d_in[12];
    const float* pw  = (const float*)d_in[13];
    const float* pb  = (const float*)d_in[14];
    const float* lg  = (const float*)d_in[15];
    const float* lb  = (const float*)d_in[16];
    float* out = (float*)d_out;

    // ---- workspace layout (~97 MB) ----
    float* fb = (float*)d_ws;
    float* cc   = fb;                 // 32K f
    float* ls0  = cc + 32768;         // 32K f
    float* ls1  = ls0 + 32768;        // 32K f
    float* Op0  = ls1 + 32768;        // 2M f (8MB)
    float* Op1  = Op0 + 2097152;      // 2M f
    u16* us   = (u16*)(Op1 + 2097152);
    u16* qbf  = us;                   // 2M u16 (reused as Obf)
    u16* kbf  = qbf + 2097152;
    u16* vbf  = kbf + 2097152;
    u16* posb = vbf + 2097152;        // 1M
    u16* qwT  = posb + 1048576;       // 1M
    u16* kwT  = qwT + 1048576;
    u16* vwT  = kwT + 1048576;
    u16* pwT  = vwT + 1048576;
    u16* WrT  = pwT + 1048576;
    u16* qhb  = WrT + 1048576;        // 2M
    u16* keffb= qhb + 2097152;        // 2M
    u16* vTb  = keffb + 2097152;      // 2M
    u16* pq0  = vTb + 2097152;        // 2M x6 (q/k/v partials)
    u16* pq1  = pq0 + 2097152;
    u16* pk0  = pq1 + 2097152;
    u16* pk1  = pk0 + 2097152;
    u16* pv0  = pk1 + 2097152;
    u16* pv1  = pv0 + 2097152;
    u16* pr0  = pv1 + 2097152;        // 1M x2 (pos partials)
    u16* pr1  = pr0 + 1048576;
    u16* po0  = pr1 + 1048576;        // 2M x4 (post partials)
    u16* po1  = po0 + 2097152;
    u16* po2  = po1 + 2097152;
    u16* po3  = po2 + 2097152;
    u16* Obf  = qbf;

    dim3 blk(256);
    prep_all<<<12288, blk, 0, stream>>>(q, k, v, pos, qw, kw, vw, pw, rk,
                                        qbf, kbf, vbf, posb, qwT, kwT, vwT, pwT, WrT);

    GJ jq0 = {qbf,  qwT, pq0, 2048, 0,   512};
    GJ jq1 = {qbf,  qwT, pq1, 2048, 512, 512};
    GJ jk0 = {kbf,  kwT, pk0, 2048, 0,   512};
    GJ jk1 = {kbf,  kwT, pk1, 2048, 512, 512};
    GJ jv0 = {vbf,  vwT, pv0, 2048, 0,   512};
    GJ jv1 = {vbf,  vwT, pv1, 2048, 512, 512};
    GJ jp0 = {posb, WrT, pr0, 1024, 0,   512};
    GJ jp1 = {posb, WrT, pr1, 1024, 512, 512};
    gemm_p<<<dim3(8, 16, 8), blk, 0, stream>>>(jq0, jq1, jk0, jk1, jv0, jv1, jp0, jp1);

    prep2<<<6144, blk, 0, stream>>>(pk0, pk1, pr0, pr1, pv0, pv1, pq0, pq1,
                                    kbi, vbi, rwb, rrb, msk, keffb, cc, vTb, qhb);

    attn_mfma<<<1024, blk, 0, stream>>>(qhb, keffb, vTb, cc, Op0, Op1, ls0, ls1);

    comb_o<<<2048, blk, 0, stream>>>(Op0, Op1, ls0, ls1, Obf);

    GJ jo0 = {Obf, pwT, po0, 2048, 0,   256};
    GJ jo1 = {Obf, pwT, po1, 2048, 256, 256};
    GJ jo2 = {Obf, pwT, po2, 2048, 512, 256};
    GJ jo3 = {Obf, pwT, po3, 2048, 768, 256};
    gemm_p<<<dim3(8, 16, 4), blk, 0, stream>>>(jo0, jo1, jo2, jo3, jo0, jo0, jo0, jo0);

    ln_kernel<<<2048, blk, 0, stream>>>(po0, po1, po2, po3, q, pb, lg, lb, out);
}

// Round 5
// 224.468 us; speedup vs baseline: 1.0089x; 1.0089x over previous
//
#include <hip/hip_runtime.h>
#include <cstddef>
#include <cstdint>

typedef unsigned short u16;
typedef unsigned int   u32;

#define S_LEN  1024
#define NHEAD  16
#define HDIM   64
#define DMODEL 1024
#define NORMSC 0.125f
#define BIGC   1000000.0f
#define LOG2E  1.44269504088896f
#define SC2    (0.125f * 1.44269504088896f)

typedef __bf16 bf16x8 __attribute__((ext_vector_type(8)));
typedef float  f32x4  __attribute__((ext_vector_type(4)));

#define MFMA16(a, b, c) __builtin_amdgcn_mfma_f32_16x16x32_bf16((a), (b), (c), 0, 0, 0)

__device__ __forceinline__ u16 f2bf(float f) {
    u32 u = __float_as_uint(f);
    u32 r = (u + 0x7fffu + ((u >> 16) & 1u)) >> 16;
    return (u16)r;
}
__device__ __forceinline__ float bf2f(u32 v) {
    return __uint_as_float(v << 16);
}
__device__ __forceinline__ float4 unp4(uint2 u) {
    float4 f;
    f.x = bf2f(u.x & 0xffffu); f.y = bf2f(u.x >> 16);
    f.z = bf2f(u.y & 0xffffu); f.w = bf2f(u.y >> 16);
    return f;
}
__device__ __forceinline__ void async16(const void* g, void* l) {
    __builtin_amdgcn_global_load_lds(
        (__attribute__((address_space(1))) void*)(g),
        (__attribute__((address_space(3))) void*)(l), 16, 0, 0);
}

// ---------------- prep_all: fp32->bf16 conversions + weight transposes ----------------
__global__ __launch_bounds__(256) void prep_all(
    const float* q, const float* k, const float* v, const float* pos,
    const float* qw, const float* kw, const float* vw, const float* pw, const float* rk,
    u16* qbf, u16* kbf, u16* vbf, u16* posb,
    u16* qwT, u16* kwT, u16* vwT, u16* pwT, u16* WrT)
{
    __shared__ float tb[32][33];
    const int bid = blockIdx.x, tid = threadIdx.x;
    if (bid < 7168) {
        const float* s; u16* d; int base;
        if (bid < 2048)      { s = q;   d = qbf;  base = bid; }
        else if (bid < 4096) { s = k;   d = kbf;  base = bid - 2048; }
        else if (bid < 6144) { s = v;   d = vbf;  base = bid - 4096; }
        else                 { s = pos; d = posb; base = bid - 6144; }
        const int i = base * 1024 + tid * 4;
        const float4 val = *(const float4*)&s[i];
        uint2 o;
        o.x = (u32)f2bf(val.x) | ((u32)f2bf(val.y) << 16);
        o.y = (u32)f2bf(val.z) | ((u32)f2bf(val.w) << 16);
        *(uint2*)&d[i] = o;
        return;
    }
    const int t = bid - 7168;
    const float* in; u16* out; int ild, r0, c0;
    if (t < 4096) {
        const int ts = t & 1023;
        if (t < 1024)      { in = qw; out = qwT; }
        else if (t < 2048) { in = kw; out = kwT; }
        else if (t < 3072) { in = vw; out = vwT; }
        else               { in = pw; out = pwT; }
        ild = 1024;
        r0 = (ts >> 5) * 32; c0 = (ts & 31) * 32;
    } else {
        const int ts = t - 4096;
        const int n = ts >> 6, tt = ts & 63;
        in = rk + (size_t)n * 65536; out = WrT + (size_t)n * 65536;
        ild = 64;
        r0 = (tt >> 1) * 32; c0 = (tt & 1) * 32;
    }
    const int tx = tid & 31, ty = tid >> 5;
    for (int i = ty; i < 32; i += 8)
        tb[i][tx] = in[(size_t)(r0 + i) * ild + c0 + tx];
    __syncthreads();
    for (int i = ty; i < 32; i += 8)
        out[(size_t)(c0 + i) * 1024 + r0 + tx] = f2bf(tb[tx][i]);
}

// ---------------- MFMA bf16 GEMM, bf16 row-major partial output ----------------
// C(Mx1024 bf16) = A(Mx1024) @ Bt(1024x1024)^T over k in [k0, k0+klen)
struct GJ { const u16* A; const u16* Bt; u16* C; int M; int k0; int klen; };

__global__ __launch_bounds__(256) void gemm_p(
    GJ j0, GJ j1, GJ j2, GJ j3, GJ j4, GJ j5, GJ j6, GJ j7)
{
    GJ g;
    switch (blockIdx.z) {
        case 0: g = j0; break; case 1: g = j1; break;
        case 2: g = j2; break; case 3: g = j3; break;
        case 4: g = j4; break; case 5: g = j5; break;
        case 6: g = j6; break; default: g = j7;
    }
    const int bm = blockIdx.y * 128;
    if (bm >= g.M) return;
    const int bn = blockIdx.x * 128;
    __shared__ u16 As[4096];  // 128 rows x 32 k, 8KB
    __shared__ u16 Bs[4096];
    const int tid = threadIdx.x;
    const int w = tid >> 6, lane = tid & 63;
    const int wm = (w >> 1) * 64, wn = (w & 1) * 64;
    const int l15 = lane & 15, l16 = lane >> 4;
    f32x4 acc[4][4] = {};
    const char* Ab = (const char*)g.A;
    const char* Bb = (const char*)g.Bt;
    const int kend = g.k0 + g.klen;
    for (int k0 = g.k0; k0 < kend; k0 += 32) {
        __syncthreads();
#pragma unroll
        for (int i = 0; i < 2; ++i) {
            const int m = (i * 4 + w) * 1024 + lane * 16;
            const int r = m >> 6, cb = m & 63;
            async16(Ab + ((size_t)(bm + r) * 1024 + k0) * 2 + cb, (char*)As + m);
            async16(Bb + ((size_t)(bn + r) * 1024 + k0) * 2 + cb, (char*)Bs + m);
        }
        __syncthreads();
        bf16x8 af[4], bfr[4];
#pragma unroll
        for (int i = 0; i < 4; ++i)
            af[i] = *(const bf16x8*)&As[(wm + i * 16 + l15) * 32 + l16 * 8];
#pragma unroll
        for (int j = 0; j < 4; ++j)
            bfr[j] = *(const bf16x8*)&Bs[(wn + j * 16 + l15) * 32 + l16 * 8];
#pragma unroll
        for (int i = 0; i < 4; ++i)
#pragma unroll
            for (int j = 0; j < 4; ++j)
                acc[i][j] = MFMA16(af[i], bfr[j], acc[i][j]);
    }
#pragma unroll
    for (int i = 0; i < 4; ++i)
#pragma unroll
        for (int j = 0; j < 4; ++j) {
            const int c = bn + wn + j * 16 + l15;
#pragma unroll
            for (int rg = 0; rg < 4; ++rg) {
                const int m = bm + wm + i * 16 + l16 * 4 + rg;
                g.C[(size_t)m * 1024 + c] = f2bf(acc[i][j][rg]);
            }
        }
}

// ---------------- prep2: combine split-K partials into keff/cc, vT, qh ----------------
__global__ __launch_bounds__(256) void prep2(
    const u16* pk0, const u16* pk1, const u16* pr0, const u16* pr1,
    const u16* pv0, const u16* pv1, const u16* pq0, const u16* pq1,
    const float* kbi, const float* vbi, const float* rwb, const float* rrb,
    const int* mask, u16* keff, float* cc, u16* vT, u16* qhb)
{
    __shared__ float tb[32][33];
    const int bid = blockIdx.x, tid = threadIdx.x;
    if (bid < 2048) {
        const int t = bid * 256 + tid;
        const int row = t >> 4, li = t & 15;
        const int n = (row >> 10) & 15, kk = row & 1023, b = row >> 14;
        const size_t mi = ((size_t)(b * 1024 + kk)) * 1024 + n * 64 + li * 4;
        const size_t pi = ((size_t)kk) * 1024 + n * 64 + li * 4;
        const float4 k0v = unp4(*(const uint2*)&pk0[mi]);
        const float4 k1v = unp4(*(const uint2*)&pk1[mi]);
        const float4 r0v = unp4(*(const uint2*)&pr0[pi]);
        const float4 r1v = unp4(*(const uint2*)&pr1[pi]);
        const float4 kb4 = *(const float4*)&kbi[n * 64 + li * 4];
        float4 kv, rv;
        kv.x = k0v.x + k1v.x + kb4.x; kv.y = k0v.y + k1v.y + kb4.y;
        kv.z = k0v.z + k1v.z + kb4.z; kv.w = k0v.w + k1v.w + kb4.w;
        rv.x = r0v.x + r1v.x; rv.y = r0v.y + r1v.y;
        rv.z = r0v.z + r1v.z; rv.w = r0v.w + r1v.w;
        const float4 w1 = *(const float4*)&rwb[n * 64 + li * 4];
        const float4 w2 = *(const float4*)&rrb[n * 64 + li * 4];
        float s = w1.x * kv.x + w1.y * kv.y + w1.z * kv.z + w1.w * kv.w
                + w2.x * rv.x + w2.y * rv.y + w2.z * rv.z + w2.w * rv.w;
        uint2 o;
        o.x = (u32)f2bf(kv.x + rv.x) | ((u32)f2bf(kv.y + rv.y) << 16);
        o.y = (u32)f2bf(kv.z + rv.z) | ((u32)f2bf(kv.w + rv.w) << 16);
        *(uint2*)&keff[(size_t)row * 64 + li * 4] = o;
#pragma unroll
        for (int m = 1; m < 16; m <<= 1) s += __shfl_xor(s, m);
        if (li == 0)
            cc[row] = LOG2E * (NORMSC * s - BIGC * (float)mask[b * 1024 + kk]);
        return;
    }
    if (bid < 4096) {
        const int t = bid - 2048;
        const int head = t >> 6, tt = t & 63;
        const int b = head >> 4, n = head & 15;
        const int r0 = (tt >> 1) * 32, c0 = (tt & 1) * 32;
        const int tx = tid & 31, ty = tid >> 5;
        const float vb = vbi[n * 64 + c0 + tx];
        for (int i = ty; i < 32; i += 8) {
            const size_t idx = ((size_t)(b * 1024 + r0 + i)) * 1024 + n * 64 + c0 + tx;
            tb[i][tx] = bf2f(pv0[idx]) + bf2f(pv1[idx]) + vb;
        }
        __syncthreads();
        u16* out = vT + (size_t)head * 65536;
        for (int i = ty; i < 32; i += 8)
            out[(size_t)(c0 + i) * 1024 + r0 + tx] = f2bf(tb[tx][i]);
        return;
    }
    const int t = bid - 4096;
    const int e = t * 1024 + tid * 4;
    const int m = e >> 10, c = e & 1023;
    const float4 a = unp4(*(const uint2*)&pq0[e]);
    const float4 b4 = unp4(*(const uint2*)&pq1[e]);
    uint2 o;
    o.x = (u32)f2bf(a.x + b4.x) | ((u32)f2bf(a.y + b4.y) << 16);
    o.y = (u32)f2bf(a.z + b4.z) | ((u32)f2bf(a.w + b4.w) << 16);
    const int b2 = m >> 10, l = m & 1023, n = c >> 6, h = c & 63;
    *(uint2*)&qhb[(((size_t)(b2 * NHEAD + n)) * 1024 + l) * 64 + h] = o;
}

// ---------------- MFMA flash attention, low-LDS / high-occupancy ----------------
// 1024 blocks x 128 threads (2 waves): block = (head, 32 q-rows); 16 chunks of 64 keys.
// LDS 20KB -> 8 blocks/CU = 16 waves/CU for barrier-drain overlap.
// Rotation-swizzled LDS (mod 8); no online max (scores bounded; masked -> exp2(-1.44e6)=0).
__global__ __launch_bounds__(128) void attn_mfma(
    const u16* qb, const u16* kb, const u16* vtb, const float* ccomb, u16* O)
{
    __shared__ u16   Ks[4096];      // 64 keys x 64 h rotated, 8KB
    __shared__ u16   Vs[4096];      // 64 h x 64 keys rotated, 8KB
    __shared__ __bf16 Ps[2][1024];  // per-wave 16x64 P rotated, 4KB
    const int tid = threadIdx.x;
    const int w = tid >> 6, lane = tid & 63;
    const int l15 = lane & 15, l16 = lane >> 4;
    const int head = blockIdx.x >> 5;          // b*16+n
    const int q0 = (blockIdx.x & 31) * 32;
    const int b = head >> 4, n = head & 15;
    const size_t hoff = (size_t)head * 65536;
    const u16* qh = qb + hoff;
    const char* khc = (const char*)(kb + hoff);
    const char* vtc = (const char*)(vtb + hoff);
    const float* cc = ccomb + head * 1024;
    __bf16* Pw = Ps[w];

    bf16x8 qf[2];
    {
        const size_t rb = ((size_t)(q0 + w * 16 + l15)) * 64 + l16 * 8;
        qf[0] = *(const bf16x8*)&qh[rb];
        qf[1] = *(const bf16x8*)&qh[rb + 32];
    }
    f32x4 Oacc[4] = {};
    float lsum[4] = {};

    for (int kc = 0; kc < 16; ++kc) {
        __syncthreads();  // all waves done reading previous Ks/Vs
        // stage K chunk (64 keys x 128B rows) + V^T chunk (64 h x 128B)
#pragma unroll
        for (int i = 0; i < 4; ++i) {
            const int r = w * 32 + i * 8 + (lane >> 3);
            const int c = lane & 7;
            async16(khc + kc * 8192 + r * 128 + (((c + r) & 7) << 4),
                    (char*)Ks + r * 128 + c * 16);
            async16(vtc + (size_t)r * 2048 + kc * 128 + (((c + r) & 7) << 4),
                    (char*)Vs + r * 128 + c * 16);
        }
        __syncthreads();  // vmcnt drained at barrier -> staging complete

        // QK^T: 4 col-tiles of 16 keys
        f32x4 sc[4];
#pragma unroll
        for (int j = 0; j < 4; ++j) {
            const int rk2 = j * 16 + l15;
            const int base = rk2 * 64;
            f32x4 a = {0.f, 0.f, 0.f, 0.f};
            a = MFMA16(qf[0], *(const bf16x8*)&Ks[base + (((l16 - rk2) & 7) << 3)], a);
            a = MFMA16(qf[1], *(const bf16x8*)&Ks[base + (((l16 + 4 - rk2) & 7) << 3)], a);
            const float cadd = cc[kc * 64 + j * 16 + l15];
            sc[j] = a * SC2 + cadd;
        }
        // exp (no max subtraction) + P write (rotated mod 8)
#pragma unroll
        for (int j = 0; j < 4; ++j) {
            const int cg = j * 2 + (l15 >> 3);
#pragma unroll
            for (int rg = 0; rg < 4; ++rg) {
                const float p = exp2f(sc[j][rg]);
                lsum[rg] += p;
                const int row = l16 * 4 + rg;
                Pw[row * 64 + (((cg - row) & 7) << 3) + (l15 & 7)] = (__bf16)p;
            }
        }
        // PV: O(16x64) += P(16x64) @ V(64x64); P per-wave -> in-wave lgkm dependency only
        bf16x8 pf[2];
#pragma unroll
        for (int f = 0; f < 2; ++f)
            pf[f] = *(const bf16x8*)&Pw[l15 * 64 + (((f * 4 + l16 - l15) & 7) << 3)];
#pragma unroll
        for (int t4 = 0; t4 < 4; ++t4) {
#pragma unroll
            for (int f = 0; f < 2; ++f) {
                const int vr = t4 * 16 + l15;
                const int ch = f * 4 + l16;
                const bf16x8 vf = *(const bf16x8*)&Vs[vr * 64 + (((ch - vr) & 7) << 3)];
                Oacc[t4] = MFMA16(pf[f], vf, Oacc[t4]);
            }
        }
    }
    // final row-sum reduce across the 16 l15 lanes, normalize, write bf16 O
    float inv[4];
#pragma unroll
    for (int rg = 0; rg < 4; ++rg) {
        float s = lsum[rg];
#pragma unroll
        for (int m = 1; m < 16; m <<= 1) s += __shfl_xor(s, m);
        inv[rg] = 1.0f / s;
    }
#pragma unroll
    for (int t4 = 0; t4 < 4; ++t4) {
#pragma unroll
        for (int rg = 0; rg < 4; ++rg) {
            const int srow = q0 + w * 16 + l16 * 4 + rg;
            const int col = n * 64 + t4 * 16 + l15;
            O[((size_t)b * 1024 + srow) * 1024 + col] = f2bf(Oacc[t4][rg] * inv[rg]);
        }
    }
}

// ---------------- layernorm: out = LN(po0+po1+po2+po3 + post_b + resid) ----------------
__global__ __launch_bounds__(256) void ln_kernel(
    const u16* __restrict__ p0, const u16* __restrict__ p1,
    const u16* __restrict__ p2, const u16* __restrict__ p3,
    const float* __restrict__ resid, const float* __restrict__ pb,
    const float* __restrict__ g, const float* __restrict__ bb,
    float* __restrict__ out)
{
    const int row = blockIdx.x;
    const int tid = threadIdx.x;
    const size_t i = (size_t)row * DMODEL + tid * 4;
    const float4 a0 = unp4(*(const uint2*)&p0[i]);
    const float4 a1 = unp4(*(const uint2*)&p1[i]);
    const float4 a2 = unp4(*(const uint2*)&p2[i]);
    const float4 a3 = unp4(*(const uint2*)&p3[i]);
    const float4 rr = *(const float4*)&resid[i];
    const float4 pv = *(const float4*)&pb[tid * 4];
    float4 v;
    v.x = a0.x + a1.x + a2.x + a3.x + rr.x + pv.x;
    v.y = a0.y + a1.y + a2.y + a3.y + rr.y + pv.y;
    v.z = a0.z + a1.z + a2.z + a3.z + rr.z + pv.z;
    v.w = a0.w + a1.w + a2.w + a3.w + rr.w + pv.w;
    float s1 = v.x + v.y + v.z + v.w;
    float s2 = v.x * v.x + v.y * v.y + v.z * v.z + v.w * v.w;
#pragma unroll
    for (int off = 32; off; off >>= 1) {
        s1 += __shfl_down(s1, off);
        s2 += __shfl_down(s2, off);
    }
    __shared__ float rb[8];
    if ((tid & 63) == 0) { rb[tid >> 6] = s1; rb[4 + (tid >> 6)] = s2; }
    __syncthreads();
    if (tid == 0) {
        rb[0] = rb[0] + rb[1] + rb[2] + rb[3];
        rb[4] = rb[4] + rb[5] + rb[6] + rb[7];
    }
    __syncthreads();
    s1 = rb[0]; s2 = rb[4];
    const float mu = s1 * (1.0f / DMODEL);
    const float var = s2 * (1.0f / DMODEL) - mu * mu;
    const float rstd = rsqrtf(var + 1e-5f);
    const float4 gv = *(const float4*)&g[tid * 4];
    const float4 bv = *(const float4*)&bb[tid * 4];
    float4 o;
    o.x = (v.x - mu) * rstd * gv.x + bv.x;
    o.y = (v.y - mu) * rstd * gv.y + bv.y;
    o.z = (v.z - mu) * rstd * gv.z + bv.z;
    o.w = (v.w - mu) * rstd * gv.w + bv.w;
    *(float4*)&out[i] = o;
}

extern "C" void kernel_launch(void* const* d_in, const int* in_sizes, int n_in,
                              void* d_out, int out_size, void* d_ws, size_t ws_size,
                              hipStream_t stream)
{
    (void)in_sizes; (void)n_in; (void)out_size; (void)ws_size;
    const float* q   = (const float*)d_in[0];
    const float* k   = (const float*)d_in[1];
    const float* v   = (const float*)d_in[2];
    const float* pos = (const float*)d_in[3];
    const int*   msk = (const int*)d_in[4];
    const float* qw  = (const float*)d_in[5];
    const float* kw  = (const float*)d_in[6];
    const float* kbi = (const float*)d_in[7];
    const float* vw  = (const float*)d_in[8];
    const float* vbi = (const float*)d_in[9];
    const float* rwb = (const float*)d_in[10];
    const float* rrb = (const float*)d_in[11];
    const float* rk  = (const float*)d_in[12];
    const float* pw  = (const float*)d_in[13];
    const float* pb  = (const float*)d_in[14];
    const float* lg  = (const float*)d_in[15];
    const float* lb  = (const float*)d_in[16];
    float* out = (float*)d_out;

    // ---- workspace layout (~81 MB) ----
    float* fb = (float*)d_ws;
    float* cc   = fb;                 // 32K f
    u16* us   = (u16*)(cc + 32768);
    u16* qbf  = us;                   // 2M u16 (reused as Obf)
    u16* kbf  = qbf + 2097152;
    u16* vbf  = kbf + 2097152;
    u16* posb = vbf + 2097152;        // 1M
    u16* qwT  = posb + 1048576;       // 1M
    u16* kwT  = qwT + 1048576;
    u16* vwT  = kwT + 1048576;
    u16* pwT  = vwT + 1048576;
    u16* WrT  = pwT + 1048576;
    u16* qhb  = WrT + 1048576;        // 2M
    u16* keffb= qhb + 2097152;        // 2M
    u16* vTb  = keffb + 2097152;      // 2M
    u16* pq0  = vTb + 2097152;        // 2M x6 (q/k/v partials)
    u16* pq1  = pq0 + 2097152;
    u16* pk0  = pq1 + 2097152;
    u16* pk1  = pk0 + 2097152;
    u16* pv0  = pk1 + 2097152;
    u16* pv1  = pv0 + 2097152;
    u16* pr0  = pv1 + 2097152;        // 1M x2 (pos partials)
    u16* pr1  = pr0 + 1048576;
    u16* po0  = pr1 + 1048576;        // 2M x4 (post partials)
    u16* po1  = po0 + 2097152;
    u16* po2  = po1 + 2097152;
    u16* po3  = po2 + 2097152;
    u16* Obf  = qbf;

    dim3 blk(256);
    prep_all<<<12288, blk, 0, stream>>>(q, k, v, pos, qw, kw, vw, pw, rk,
                                        qbf, kbf, vbf, posb, qwT, kwT, vwT, pwT, WrT);

    GJ jq0 = {qbf,  qwT, pq0, 2048, 0,   512};
    GJ jq1 = {qbf,  qwT, pq1, 2048, 512, 512};
    GJ jk0 = {kbf,  kwT, pk0, 2048, 0,   512};
    GJ jk1 = {kbf,  kwT, pk1, 2048, 512, 512};
    GJ jv0 = {vbf,  vwT, pv0, 2048, 0,   512};
    GJ jv1 = {vbf,  vwT, pv1, 2048, 512, 512};
    GJ jp0 = {posb, WrT, pr0, 1024, 0,   512};
    GJ jp1 = {posb, WrT, pr1, 1024, 512, 512};
    gemm_p<<<dim3(8, 16, 8), blk, 0, stream>>>(jq0, jq1, jk0, jk1, jv0, jv1, jp0, jp1);

    prep2<<<6144, blk, 0, stream>>>(pk0, pk1, pr0, pr1, pv0, pv1, pq0, pq1,
                                    kbi, vbi, rwb, rrb, msk, keffb, cc, vTb, qhb);

    attn_mfma<<<1024, dim3(128), 0, stream>>>(qhb, keffb, vTb, cc, Obf);

    GJ jo0 = {Obf, pwT, po0, 2048, 0,   256};
    GJ jo1 = {Obf, pwT, po1, 2048, 256, 256};
    GJ jo2 = {Obf, pwT, po2, 2048, 512, 256};
    GJ jo3 = {Obf, pwT, po3, 2048, 768, 256};
    gemm_p<<<dim3(8, 16, 4), blk, 0, stream>>>(jo0, jo1, jo2, jo3, jo0, jo0, jo0, jo0);

    ln_kernel<<<2048, blk, 0, stream>>>(po0, po1, po2, po3, q, pb, lg, lb, out);
}

// Round 6
// 212.779 us; speedup vs baseline: 1.0643x; 1.0549x over previous
//
#include <hip/hip_runtime.h>
#include <cstddef>
#include <cstdint>

typedef unsigned short u16;
typedef unsigned int   u32;

#define S_LEN  1024
#define NHEAD  16
#define HDIM   64
#define DMODEL 1024
#define NORMSC 0.125f
#define BIGC   1000000.0f
#define LOG2E  1.44269504088896f
#define SC2    (0.125f * 1.44269504088896f)

typedef __bf16 bf16x8 __attribute__((ext_vector_type(8)));
typedef float  f32x4  __attribute__((ext_vector_type(4)));

#define MFMA16(a, b, c) __builtin_amdgcn_mfma_f32_16x16x32_bf16((a), (b), (c), 0, 0, 0)

__device__ __forceinline__ u16 f2bf(float f) {
    u32 u = __float_as_uint(f);
    u32 r = (u + 0x7fffu + ((u >> 16) & 1u)) >> 16;
    return (u16)r;
}
__device__ __forceinline__ float bf2f(u32 v) {
    return __uint_as_float(v << 16);
}
__device__ __forceinline__ float4 unp4(uint2 u) {
    float4 f;
    f.x = bf2f(u.x & 0xffffu); f.y = bf2f(u.x >> 16);
    f.z = bf2f(u.y & 0xffffu); f.w = bf2f(u.y >> 16);
    return f;
}
__device__ __forceinline__ void async16(const void* g, void* l) {
    __builtin_amdgcn_global_load_lds(
        (__attribute__((address_space(1))) void*)(g),
        (__attribute__((address_space(3))) void*)(l), 16, 0, 0);
}

// ---------------- prep_all: fp32->bf16 conversions + weight transposes ----------------
__global__ __launch_bounds__(256) void prep_all(
    const float* q, const float* k, const float* v, const float* pos,
    const float* qw, const float* kw, const float* vw, const float* pw, const float* rk,
    u16* qbf, u16* kbf, u16* vbf, u16* posb,
    u16* qwT, u16* kwT, u16* vwT, u16* pwT, u16* WrT)
{
    __shared__ float tb[32][33];
    const int bid = blockIdx.x, tid = threadIdx.x;
    if (bid < 7168) {
        const float* s; u16* d; int base;
        if (bid < 2048)      { s = q;   d = qbf;  base = bid; }
        else if (bid < 4096) { s = k;   d = kbf;  base = bid - 2048; }
        else if (bid < 6144) { s = v;   d = vbf;  base = bid - 4096; }
        else                 { s = pos; d = posb; base = bid - 6144; }
        const int i = base * 1024 + tid * 4;
        const float4 val = *(const float4*)&s[i];
        uint2 o;
        o.x = (u32)f2bf(val.x) | ((u32)f2bf(val.y) << 16);
        o.y = (u32)f2bf(val.z) | ((u32)f2bf(val.w) << 16);
        *(uint2*)&d[i] = o;
        return;
    }
    const int t = bid - 7168;
    const float* in; u16* out; int ild, r0, c0;
    if (t < 4096) {
        const int ts = t & 1023;
        if (t < 1024)      { in = qw; out = qwT; }
        else if (t < 2048) { in = kw; out = kwT; }
        else if (t < 3072) { in = vw; out = vwT; }
        else               { in = pw; out = pwT; }
        ild = 1024;
        r0 = (ts >> 5) * 32; c0 = (ts & 31) * 32;
    } else {
        const int ts = t - 4096;
        const int n = ts >> 6, tt = ts & 63;
        in = rk + (size_t)n * 65536; out = WrT + (size_t)n * 65536;
        ild = 64;
        r0 = (tt >> 1) * 32; c0 = (tt & 1) * 32;
    }
    const int tx = tid & 31, ty = tid >> 5;
    for (int i = ty; i < 32; i += 8)
        tb[i][tx] = in[(size_t)(r0 + i) * ild + c0 + tx];
    __syncthreads();
    for (int i = ty; i < 32; i += 8)
        out[(size_t)(c0 + i) * 1024 + r0 + tx] = f2bf(tb[tx][i]);
}

// ---------------- MFMA bf16 GEMM, double-buffered staging, bf16 partial output ----------------
// C(Mx1024 bf16) = A(Mx1024) @ Bt(1024x1024)^T over k in [k0, k0+klen)
struct GJ { const u16* A; const u16* Bt; u16* C; int M; int k0; int klen; };

__global__ __launch_bounds__(256) void gemm_p(
    GJ j0, GJ j1, GJ j2, GJ j3, GJ j4, GJ j5, GJ j6, GJ j7)
{
    GJ g;
    switch (blockIdx.z) {
        case 0: g = j0; break; case 1: g = j1; break;
        case 2: g = j2; break; case 3: g = j3; break;
        case 4: g = j4; break; case 5: g = j5; break;
        case 6: g = j6; break; default: g = j7;
    }
    const int bm = blockIdx.y * 128;
    if (bm >= g.M) return;
    const int bn = blockIdx.x * 128;
    __shared__ u16 As[2][4096];  // 2 x (128 rows x 32 k) 8KB
    __shared__ u16 Bs[2][4096];
    const int tid = threadIdx.x;
    const int w = tid >> 6, lane = tid & 63;
    const int wm = (w >> 1) * 64, wn = (w & 1) * 64;
    const int l15 = lane & 15, l16 = lane >> 4;
    f32x4 acc[4][4] = {};
    const char* Ab = (const char*)g.A;
    const char* Bb = (const char*)g.Bt;
    const int kend = g.k0 + g.klen;
    const int m0 = w * 1024 + lane * 16;       // byte index, issue slice 0
    const int m1 = (4 + w) * 1024 + lane * 16; // issue slice 1
    const int r0w = m0 >> 6, cb0 = m0 & 63;
    const int r1w = m1 >> 6, cb1 = m1 & 63;
    // prologue: stage first tile into buf 0
    async16(Ab + ((size_t)(bm + r0w) * 1024 + g.k0) * 2 + cb0, (char*)As[0] + m0);
    async16(Bb + ((size_t)(bn + r0w) * 1024 + g.k0) * 2 + cb0, (char*)Bs[0] + m0);
    async16(Ab + ((size_t)(bm + r1w) * 1024 + g.k0) * 2 + cb1, (char*)As[0] + m1);
    async16(Bb + ((size_t)(bn + r1w) * 1024 + g.k0) * 2 + cb1, (char*)Bs[0] + m1);
    int buf = 0;
    for (int k0 = g.k0; k0 < kend; k0 += 32) {
        __syncthreads();  // drains vmcnt: buf ready; all waves done reading buf^1
        const int kn = k0 + 32;
        if (kn < kend) {  // prefetch next tile into buf^1 (hidden under compute below)
            async16(Ab + ((size_t)(bm + r0w) * 1024 + kn) * 2 + cb0, (char*)As[buf ^ 1] + m0);
            async16(Bb + ((size_t)(bn + r0w) * 1024 + kn) * 2 + cb0, (char*)Bs[buf ^ 1] + m0);
            async16(Ab + ((size_t)(bm + r1w) * 1024 + kn) * 2 + cb1, (char*)As[buf ^ 1] + m1);
            async16(Bb + ((size_t)(bn + r1w) * 1024 + kn) * 2 + cb1, (char*)Bs[buf ^ 1] + m1);
        }
        bf16x8 af[4], bfr[4];
#pragma unroll
        for (int i = 0; i < 4; ++i)
            af[i] = *(const bf16x8*)&As[buf][(wm + i * 16 + l15) * 32 + l16 * 8];
#pragma unroll
        for (int j = 0; j < 4; ++j)
            bfr[j] = *(const bf16x8*)&Bs[buf][(wn + j * 16 + l15) * 32 + l16 * 8];
#pragma unroll
        for (int i = 0; i < 4; ++i)
#pragma unroll
            for (int j = 0; j < 4; ++j)
                acc[i][j] = MFMA16(af[i], bfr[j], acc[i][j]);
        buf ^= 1;
    }
#pragma unroll
    for (int i = 0; i < 4; ++i)
#pragma unroll
        for (int j = 0; j < 4; ++j) {
            const int c = bn + wn + j * 16 + l15;
#pragma unroll
            for (int rg = 0; rg < 4; ++rg) {
                const int m = bm + wm + i * 16 + l16 * 4 + rg;
                g.C[(size_t)m * 1024 + c] = f2bf(acc[i][j][rg]);
            }
        }
}

// ---------------- prep2: combine split-K partials into keff/cc, vT, qh ----------------
__global__ __launch_bounds__(256) void prep2(
    const u16* pk0, const u16* pk1, const u16* pr0, const u16* pr1,
    const u16* pv0, const u16* pv1, const u16* pq0, const u16* pq1,
    const float* kbi, const float* vbi, const float* rwb, const float* rrb,
    const int* mask, u16* keff, float* cc, u16* vT, u16* qhb)
{
    __shared__ float tb[32][33];
    const int bid = blockIdx.x, tid = threadIdx.x;
    if (bid < 2048) {
        const int t = bid * 256 + tid;
        const int row = t >> 4, li = t & 15;
        const int n = (row >> 10) & 15, kk = row & 1023, b = row >> 14;
        const size_t mi = ((size_t)(b * 1024 + kk)) * 1024 + n * 64 + li * 4;
        const size_t pi = ((size_t)kk) * 1024 + n * 64 + li * 4;
        const float4 k0v = unp4(*(const uint2*)&pk0[mi]);
        const float4 k1v = unp4(*(const uint2*)&pk1[mi]);
        const float4 r0v = unp4(*(const uint2*)&pr0[pi]);
        const float4 r1v = unp4(*(const uint2*)&pr1[pi]);
        const float4 kb4 = *(const float4*)&kbi[n * 64 + li * 4];
        float4 kv, rv;
        kv.x = k0v.x + k1v.x + kb4.x; kv.y = k0v.y + k1v.y + kb4.y;
        kv.z = k0v.z + k1v.z + kb4.z; kv.w = k0v.w + k1v.w + kb4.w;
        rv.x = r0v.x + r1v.x; rv.y = r0v.y + r1v.y;
        rv.z = r0v.z + r1v.z; rv.w = r0v.w + r1v.w;
        const float4 w1 = *(const float4*)&rwb[n * 64 + li * 4];
        const float4 w2 = *(const float4*)&rrb[n * 64 + li * 4];
        float s = w1.x * kv.x + w1.y * kv.y + w1.z * kv.z + w1.w * kv.w
                + w2.x * rv.x + w2.y * rv.y + w2.z * rv.z + w2.w * rv.w;
        uint2 o;
        o.x = (u32)f2bf(kv.x + rv.x) | ((u32)f2bf(kv.y + rv.y) << 16);
        o.y = (u32)f2bf(kv.z + rv.z) | ((u32)f2bf(kv.w + rv.w) << 16);
        *(uint2*)&keff[(size_t)row * 64 + li * 4] = o;
#pragma unroll
        for (int m = 1; m < 16; m <<= 1) s += __shfl_xor(s, m);
        if (li == 0)
            cc[row] = LOG2E * (NORMSC * s - BIGC * (float)mask[b * 1024 + kk]);
        return;
    }
    if (bid < 4096) {
        const int t = bid - 2048;
        const int head = t >> 6, tt = t & 63;
        const int b = head >> 4, n = head & 15;
        const int r0 = (tt >> 1) * 32, c0 = (tt & 1) * 32;
        const int tx = tid & 31, ty = tid >> 5;
        const float vb = vbi[n * 64 + c0 + tx];
        for (int i = ty; i < 32; i += 8) {
            const size_t idx = ((size_t)(b * 1024 + r0 + i)) * 1024 + n * 64 + c0 + tx;
            tb[i][tx] = bf2f(pv0[idx]) + bf2f(pv1[idx]) + vb;
        }
        __syncthreads();
        u16* out = vT + (size_t)head * 65536;
        for (int i = ty; i < 32; i += 8)
            out[(size_t)(c0 + i) * 1024 + r0 + tx] = f2bf(tb[tx][i]);
        return;
    }
    const int t = bid - 4096;
    const int e = t * 1024 + tid * 4;
    const int m = e >> 10, c = e & 1023;
    const float4 a = unp4(*(const uint2*)&pq0[e]);
    const float4 b4 = unp4(*(const uint2*)&pq1[e]);
    uint2 o;
    o.x = (u32)f2bf(a.x + b4.x) | ((u32)f2bf(a.y + b4.y) << 16);
    o.y = (u32)f2bf(a.z + b4.z) | ((u32)f2bf(a.w + b4.w) << 16);
    const int b2 = m >> 10, l = m & 1023, n = c >> 6, h = c & 63;
    *(uint2*)&qhb[(((size_t)(b2 * NHEAD + n)) * 1024 + l) * 64 + h] = o;
}

// ---------------- MFMA flash attention, double-buffered K/V staging ----------------
// 1024 blocks x 128 threads (2 waves): block = (head, 32 q-rows); 16 chunks of 64 keys.
// LDS 36KB -> 4 blocks/CU; prefetch chunk kc+1 while computing kc so the barrier's
// vmcnt(0) drain waits on loads that already had a full compute phase to land.
// Rotation-swizzled LDS (mod 8); no online max (scores bounded; masked -> exp2(-1.44e6)=0).
__global__ __launch_bounds__(128) void attn_mfma(
    const u16* qb, const u16* kb, const u16* vtb, const float* ccomb, u16* O)
{
    __shared__ u16   Ks[2][4096];   // 2 x (64 keys x 64 h rotated) 16KB
    __shared__ u16   Vs[2][4096];   // 2 x (64 h x 64 keys rotated) 16KB
    __shared__ __bf16 Ps[2][1024];  // per-wave 16x64 P rotated, 4KB
    const int tid = threadIdx.x;
    const int w = tid >> 6, lane = tid & 63;
    const int l15 = lane & 15, l16 = lane >> 4;
    const int head = blockIdx.x >> 5;          // b*16+n
    const int q0 = (blockIdx.x & 31) * 32;
    const int b = head >> 4, n = head & 15;
    const size_t hoff = (size_t)head * 65536;
    const u16* qh = qb + hoff;
    const char* khc = (const char*)(kb + hoff);
    const char* vtc = (const char*)(vtb + hoff);
    const float* cc = ccomb + head * 1024;
    __bf16* Pw = Ps[w];

    bf16x8 qf[2];
    {
        const size_t rb = ((size_t)(q0 + w * 16 + l15)) * 64 + l16 * 8;
        qf[0] = *(const bf16x8*)&qh[rb];
        qf[1] = *(const bf16x8*)&qh[rb + 32];
    }
    f32x4 Oacc[4] = {};
    float lsum[4] = {};

    // per-lane staging addresses (wave-uniform LDS base + lane*16 pattern)
    const int sr0 = w * 32 + (lane >> 3);        // K rows: +8 per iter
    const int sc0 = lane & 7;
    // prologue: stage chunk 0 into buf 0
#pragma unroll
    for (int i = 0; i < 4; ++i) {
        const int r = sr0 + i * 8;
        async16(khc + r * 128 + (((sc0 + r) & 7) << 4), (char*)Ks[0] + r * 128 + sc0 * 16);
        async16(vtc + (size_t)r * 2048 + (((sc0 + r) & 7) << 4), (char*)Vs[0] + r * 128 + sc0 * 16);
    }
    int buf = 0;
    for (int kc = 0; kc < 16; ++kc) {
        __syncthreads();  // buf's loads drained; all waves done reading buf^1
        if (kc < 15) {    // prefetch next chunk into buf^1
            const int kn = kc + 1;
#pragma unroll
            for (int i = 0; i < 4; ++i) {
                const int r = sr0 + i * 8;
                async16(khc + kn * 8192 + r * 128 + (((sc0 + r) & 7) << 4),
                        (char*)Ks[buf ^ 1] + r * 128 + sc0 * 16);
                async16(vtc + (size_t)r * 2048 + kn * 128 + (((sc0 + r) & 7) << 4),
                        (char*)Vs[buf ^ 1] + r * 128 + sc0 * 16);
            }
        }
        const u16* Kb = Ks[buf];
        const u16* Vb = Vs[buf];
        // QK^T: 4 col-tiles of 16 keys
        f32x4 sc[4];
#pragma unroll
        for (int j = 0; j < 4; ++j) {
            const int rk2 = j * 16 + l15;
            const int base = rk2 * 64;
            f32x4 a = {0.f, 0.f, 0.f, 0.f};
            a = MFMA16(qf[0], *(const bf16x8*)&Kb[base + (((l16 - rk2) & 7) << 3)], a);
            a = MFMA16(qf[1], *(const bf16x8*)&Kb[base + (((l16 + 4 - rk2) & 7) << 3)], a);
            const float cadd = cc[kc * 64 + j * 16 + l15];
            sc[j] = a * SC2 + cadd;
        }
        // exp (no max subtraction) + P write (rotated mod 8)
#pragma unroll
        for (int j = 0; j < 4; ++j) {
            const int cg = j * 2 + (l15 >> 3);
#pragma unroll
            for (int rg = 0; rg < 4; ++rg) {
                const float p = exp2f(sc[j][rg]);
                lsum[rg] += p;
                const int row = l16 * 4 + rg;
                Pw[row * 64 + (((cg - row) & 7) << 3) + (l15 & 7)] = (__bf16)p;
            }
        }
        // PV: O(16x64) += P(16x64) @ V(64x64); P per-wave -> in-wave lgkm dependency only
        bf16x8 pf[2];
#pragma unroll
        for (int f = 0; f < 2; ++f)
            pf[f] = *(const bf16x8*)&Pw[l15 * 64 + (((f * 4 + l16 - l15) & 7) << 3)];
#pragma unroll
        for (int t4 = 0; t4 < 4; ++t4) {
#pragma unroll
            for (int f = 0; f < 2; ++f) {
                const int vr = t4 * 16 + l15;
                const int ch = f * 4 + l16;
                const bf16x8 vf = *(const bf16x8*)&Vb[vr * 64 + (((ch - vr) & 7) << 3)];
                Oacc[t4] = MFMA16(pf[f], vf, Oacc[t4]);
            }
        }
        buf ^= 1;
    }
    // final row-sum reduce across the 16 l15 lanes, normalize, write bf16 O
    float inv[4];
#pragma unroll
    for (int rg = 0; rg < 4; ++rg) {
        float s = lsum[rg];
#pragma unroll
        for (int m = 1; m < 16; m <<= 1) s += __shfl_xor(s, m);
        inv[rg] = 1.0f / s;
    }
#pragma unroll
    for (int t4 = 0; t4 < 4; ++t4) {
#pragma unroll
        for (int rg = 0; rg < 4; ++rg) {
            const int srow = q0 + w * 16 + l16 * 4 + rg;
            const int col = n * 64 + t4 * 16 + l15;
            O[((size_t)b * 1024 + srow) * 1024 + col] = f2bf(Oacc[t4][rg] * inv[rg]);
        }
    }
}

// ---------------- layernorm: out = LN(po0+po1+po2+po3 + post_b + resid) ----------------
__global__ __launch_bounds__(256) void ln_kernel(
    const u16* __restrict__ p0, const u16* __restrict__ p1,
    const u16* __restrict__ p2, const u16* __restrict__ p3,
    const float* __restrict__ resid, const float* __restrict__ pb,
    const float* __restrict__ g, const float* __restrict__ bb,
    float* __restrict__ out)
{
    const int row = blockIdx.x;
    const int tid = threadIdx.x;
    const size_t i = (size_t)row * DMODEL + tid * 4;
    const float4 a0 = unp4(*(const uint2*)&p0[i]);
    const float4 a1 = unp4(*(const uint2*)&p1[i]);
    const float4 a2 = unp4(*(const uint2*)&p2[i]);
    const float4 a3 = unp4(*(const uint2*)&p3[i]);
    const float4 rr = *(const float4*)&resid[i];
    const float4 pv = *(const float4*)&pb[tid * 4];
    float4 v;
    v.x = a0.x + a1.x + a2.x + a3.x + rr.x + pv.x;
    v.y = a0.y + a1.y + a2.y + a3.y + rr.y + pv.y;
    v.z = a0.z + a1.z + a2.z + a3.z + rr.z + pv.z;
    v.w = a0.w + a1.w + a2.w + a3.w + rr.w + pv.w;
    float s1 = v.x + v.y + v.z + v.w;
    float s2 = v.x * v.x + v.y * v.y + v.z * v.z + v.w * v.w;
#pragma unroll
    for (int off = 32; off; off >>= 1) {
        s1 += __shfl_down(s1, off);
        s2 += __shfl_down(s2, off);
    }
    __shared__ float rb[8];
    if ((tid & 63) == 0) { rb[tid >> 6] = s1; rb[4 + (tid >> 6)] = s2; }
    __syncthreads();
    if (tid == 0) {
        rb[0] = rb[0] + rb[1] + rb[2] + rb[3];
        rb[4] = rb[4] + rb[5] + rb[6] + rb[7];
    }
    __syncthreads();
    s1 = rb[0]; s2 = rb[4];
    const float mu = s1 * (1.0f / DMODEL);
    const float var = s2 * (1.0f / DMODEL) - mu * mu;
    const float rstd = rsqrtf(var + 1e-5f);
    const float4 gv = *(const float4*)&g[tid * 4];
    const float4 bv = *(const float4*)&bb[tid * 4];
    float4 o;
    o.x = (v.x - mu) * rstd * gv.x + bv.x;
    o.y = (v.y - mu) * rstd * gv.y + bv.y;
    o.z = (v.z - mu) * rstd * gv.z + bv.z;
    o.w = (v.w - mu) * rstd * gv.w + bv.w;
    *(float4*)&out[i] = o;
}

extern "C" void kernel_launch(void* const* d_in, const int* in_sizes, int n_in,
                              void* d_out, int out_size, void* d_ws, size_t ws_size,
                              hipStream_t stream)
{
    (void)in_sizes; (void)n_in; (void)out_size; (void)ws_size;
    const float* q   = (const float*)d_in[0];
    const float* k   = (const float*)d_in[1];
    const float* v   = (const float*)d_in[2];
    const float* pos = (const float*)d_in[3];
    const int*   msk = (const int*)d_in[4];
    const float* qw  = (const float*)d_in[5];
    const float* kw  = (const float*)d_in[6];
    const float* kbi = (const float*)d_in[7];
    const float* vw  = (const float*)d_in[8];
    const float* vbi = (const float*)d_in[9];
    const float* rwb = (const float*)d_in[10];
    const float* rrb = (const float*)d_in[11];
    const float* rk  = (const float*)d_in[12];
    const float* pw  = (const float*)d_in[13];
    const float* pb  = (const float*)d_in[14];
    const float* lg  = (const float*)d_in[15];
    const float* lb  = (const float*)d_in[16];
    float* out = (float*)d_out;

    // ---- workspace layout (~81 MB) ----
    float* fb = (float*)d_ws;
    float* cc   = fb;                 // 32K f
    u16* us   = (u16*)(cc + 32768);
    u16* qbf  = us;                   // 2M u16 (reused as Obf)
    u16* kbf  = qbf + 2097152;
    u16* vbf  = kbf + 2097152;
    u16* posb = vbf + 2097152;        // 1M
    u16* qwT  = posb + 1048576;       // 1M
    u16* kwT  = qwT + 1048576;
    u16* vwT  = kwT + 1048576;
    u16* pwT  = vwT + 1048576;
    u16* WrT  = pwT + 1048576;
    u16* qhb  = WrT + 1048576;        // 2M
    u16* keffb= qhb + 2097152;        // 2M
    u16* vTb  = keffb + 2097152;      // 2M
    u16* pq0  = vTb + 2097152;        // 2M x6 (q/k/v partials)
    u16* pq1  = pq0 + 2097152;
    u16* pk0  = pq1 + 2097152;
    u16* pk1  = pk0 + 2097152;
    u16* pv0  = pk1 + 2097152;
    u16* pv1  = pv0 + 2097152;
    u16* pr0  = pv1 + 2097152;        // 1M x2 (pos partials)
    u16* pr1  = pr0 + 1048576;
    u16* po0  = pr1 + 1048576;        // 2M x4 (post partials)
    u16* po1  = po0 + 2097152;
    u16* po2  = po1 + 2097152;
    u16* po3  = po2 + 2097152;
    u16* Obf  = qbf;

    dim3 blk(256);
    prep_all<<<12288, blk, 0, stream>>>(q, k, v, pos, qw, kw, vw, pw, rk,
                                        qbf, kbf, vbf, posb, qwT, kwT, vwT, pwT, WrT);

    GJ jq0 = {qbf,  qwT, pq0, 2048, 0,   512};
    GJ jq1 = {qbf,  qwT, pq1, 2048, 512, 512};
    GJ jk0 = {kbf,  kwT, pk0, 2048, 0,   512};
    GJ jk1 = {kbf,  kwT, pk1, 2048, 512, 512};
    GJ jv0 = {vbf,  vwT, pv0, 2048, 0,   512};
    GJ jv1 = {vbf,  vwT, pv1, 2048, 512, 512};
    GJ jp0 = {posb, WrT, pr0, 1024, 0,   512};
    GJ jp1 = {posb, WrT, pr1, 1024, 512, 512};
    gemm_p<<<dim3(8, 16, 8), blk, 0, stream>>>(jq0, jq1, jk0, jk1, jv0, jv1, jp0, jp1);

    prep2<<<6144, blk, 0, stream>>>(pk0, pk1, pr0, pr1, pv0, pv1, pq0, pq1,
                                    kbi, vbi, rwb, rrb, msk, keffb, cc, vTb, qhb);

    attn_mfma<<<1024, dim3(128), 0, stream>>>(qhb, keffb, vTb, cc, Obf);

    GJ jo0 = {Obf, pwT, po0, 2048, 0,   256};
    GJ jo1 = {Obf, pwT, po1, 2048, 256, 256};
    GJ jo2 = {Obf, pwT, po2, 2048, 512, 256};
    GJ jo3 = {Obf, pwT, po3, 2048, 768, 256};
    gemm_p<<<dim3(8, 16, 4), blk, 0, stream>>>(jo0, jo1, jo2, jo3, jo0, jo0, jo0, jo0);

    ln_kernel<<<2048, blk, 0, stream>>>(po0, po1, po2, po3, q, pb, lg, lb, out);
}

// Round 7
// 203.282 us; speedup vs baseline: 1.1140x; 1.0467x over previous
//
#include <hip/hip_runtime.h>
#include <cstddef>
#include <cstdint>

typedef unsigned short u16;
typedef unsigned int   u32;

#define S_LEN  1024
#define NHEAD  16
#define HDIM   64
#define DMODEL 1024
#define NORMSC 0.125f
#define BIGC   1000000.0f
#define LOG2E  1.44269504088896f
#define SC2    (0.125f * 1.44269504088896f)

typedef __bf16 bf16x8 __attribute__((ext_vector_type(8)));
typedef float  f32x4  __attribute__((ext_vector_type(4)));

#define MFMA16(a, b, c) __builtin_amdgcn_mfma_f32_16x16x32_bf16((a), (b), (c), 0, 0, 0)

__device__ __forceinline__ u16 f2bf(float f) {
    u32 u = __float_as_uint(f);
    u32 r = (u + 0x7fffu + ((u >> 16) & 1u)) >> 16;
    return (u16)r;
}
__device__ __forceinline__ float bf2f(u32 v) {
    return __uint_as_float(v << 16);
}
__device__ __forceinline__ float4 unp4(uint2 u) {
    float4 f;
    f.x = bf2f(u.x & 0xffffu); f.y = bf2f(u.x >> 16);
    f.z = bf2f(u.y & 0xffffu); f.w = bf2f(u.y >> 16);
    return f;
}
__device__ __forceinline__ void async16(const void* g, void* l) {
    __builtin_amdgcn_global_load_lds(
        (__attribute__((address_space(1))) void*)(g),
        (__attribute__((address_space(3))) void*)(l), 16, 0, 0);
}

// ---------------- prep_all: fp32->bf16 conversions + weight transposes ----------------
__global__ __launch_bounds__(256) void prep_all(
    const float* q, const float* k, const float* v, const float* pos,
    const float* qw, const float* kw, const float* vw, const float* pw, const float* rk,
    u16* qbf, u16* kbf, u16* vbf, u16* posb,
    u16* qwT, u16* kwT, u16* vwT, u16* pwT, u16* WrT)
{
    __shared__ float tb[32][33];
    const int bid = blockIdx.x, tid = threadIdx.x;
    if (bid < 7168) {
        const float* s; u16* d; int base;
        if (bid < 2048)      { s = q;   d = qbf;  base = bid; }
        else if (bid < 4096) { s = k;   d = kbf;  base = bid - 2048; }
        else if (bid < 6144) { s = v;   d = vbf;  base = bid - 4096; }
        else                 { s = pos; d = posb; base = bid - 6144; }
        const int i = base * 1024 + tid * 4;
        const float4 val = *(const float4*)&s[i];
        uint2 o;
        o.x = (u32)f2bf(val.x) | ((u32)f2bf(val.y) << 16);
        o.y = (u32)f2bf(val.z) | ((u32)f2bf(val.w) << 16);
        *(uint2*)&d[i] = o;
        return;
    }
    const int t = bid - 7168;
    const float* in; u16* out; int ild, r0, c0;
    if (t < 4096) {
        const int ts = t & 1023;
        if (t < 1024)      { in = qw; out = qwT; }
        else if (t < 2048) { in = kw; out = kwT; }
        else if (t < 3072) { in = vw; out = vwT; }
        else               { in = pw; out = pwT; }
        ild = 1024;
        r0 = (ts >> 5) * 32; c0 = (ts & 31) * 32;
    } else {
        const int ts = t - 4096;
        const int n = ts >> 6, tt = ts & 63;
        in = rk + (size_t)n * 65536; out = WrT + (size_t)n * 65536;
        ild = 64;
        r0 = (tt >> 1) * 32; c0 = (tt & 1) * 32;
    }
    const int tx = tid & 31, ty = tid >> 5;
    for (int i = ty; i < 32; i += 8)
        tb[i][tx] = in[(size_t)(r0 + i) * ild + c0 + tx];
    __syncthreads();
    for (int i = ty; i < 32; i += 8)
        out[(size_t)(c0 + i) * 1024 + r0 + tx] = f2bf(tb[tx][i]);
}

// ---------------- MFMA bf16 GEMM, XCD-affine 1-D grid, dbuf staging, rotated LDS ----------------
// C(Mx1024 bf16) = A(Mx1024) @ Bt(1024x1024)^T over k in [k0, k0+klen)
// nj=8: z = bid&7 (job == XCD; per-XCD set = A-half 2MB + B-half 1MB, L2-resident)
// nj=4: z = (bid&7)>>1 (half a job's M-range per XCD, ~1MB)
struct GJ { const u16* A; const u16* Bt; u16* C; int M; int k0; int klen; };

__global__ __launch_bounds__(256) void gemm_p(
    GJ j0, GJ j1, GJ j2, GJ j3, GJ j4, GJ j5, GJ j6, GJ j7, int nj)
{
    const int bid = blockIdx.x;
    const int c8 = bid & 7;
    const int x = (bid >> 3) & 7;
    int z, y;
    if (nj == 8) { z = c8; y = bid >> 6; }
    else         { z = c8 >> 1; y = ((c8 & 1) << 3) + (bid >> 6); }
    GJ g;
    switch (z) {
        case 0: g = j0; break; case 1: g = j1; break;
        case 2: g = j2; break; case 3: g = j3; break;
        case 4: g = j4; break; case 5: g = j5; break;
        case 6: g = j6; break; default: g = j7;
    }
    const int bm = y * 128;
    if (bm >= g.M) return;
    const int bn = x * 128;
    __shared__ u16 As[2][4096];  // 2 x (128 rows x 32 k, 64B rows chunk-rotated) 8KB
    __shared__ u16 Bs[2][4096];
    const int tid = threadIdx.x;
    const int w = tid >> 6, lane = tid & 63;
    const int wm = (w >> 1) * 64, wn = (w & 1) * 64;
    const int l15 = lane & 15, l16 = lane >> 4;
    f32x4 acc[4][4] = {};
    const char* Ab = (const char*)g.A;
    const char* Bb = (const char*)g.Bt;
    const int kend = g.k0 + g.klen;
    // staging slices: slice i covers LDS bytes [i*4096, i*4096+4096)
    const int m0 = w * 1024 + lane * 16;
    const int m1 = (4 + w) * 1024 + lane * 16;
    const int r0w = m0 >> 6, rc0 = ((((m0 >> 4) & 3) + r0w) & 3) << 4;  // rotated chunk
    const int r1w = m1 >> 6, rc1 = ((((m1 >> 4) & 3) + r1w) & 3) << 4;
    async16(Ab + ((size_t)(bm + r0w) * 1024 + g.k0) * 2 + rc0, (char*)As[0] + m0);
    async16(Bb + ((size_t)(bn + r0w) * 1024 + g.k0) * 2 + rc0, (char*)Bs[0] + m0);
    async16(Ab + ((size_t)(bm + r1w) * 1024 + g.k0) * 2 + rc1, (char*)As[0] + m1);
    async16(Bb + ((size_t)(bn + r1w) * 1024 + g.k0) * 2 + rc1, (char*)Bs[0] + m1);
    const int rotA = ((l16 - l15) & 3) << 3;   // u16 offset of rotated fragment chunk
    int buf = 0;
    for (int k0 = g.k0; k0 < kend; k0 += 32) {
        __syncthreads();  // buf's loads drained (vmcnt0); all waves done with buf^1
        const int kn = k0 + 32;
        if (kn < kend) {  // prefetch next tile into buf^1, hidden under compute
            async16(Ab + ((size_t)(bm + r0w) * 1024 + kn) * 2 + rc0, (char*)As[buf ^ 1] + m0);
            async16(Bb + ((size_t)(bn + r0w) * 1024 + kn) * 2 + rc0, (char*)Bs[buf ^ 1] + m0);
            async16(Ab + ((size_t)(bm + r1w) * 1024 + kn) * 2 + rc1, (char*)As[buf ^ 1] + m1);
            async16(Bb + ((size_t)(bn + r1w) * 1024 + kn) * 2 + rc1, (char*)Bs[buf ^ 1] + m1);
        }
        bf16x8 af[4], bfr[4];
#pragma unroll
        for (int i = 0; i < 4; ++i)
            af[i] = *(const bf16x8*)&As[buf][(wm + i * 16 + l15) * 32 + rotA];
#pragma unroll
        for (int j = 0; j < 4; ++j)
            bfr[j] = *(const bf16x8*)&Bs[buf][(wn + j * 16 + l15) * 32 + rotA];
#pragma unroll
        for (int i = 0; i < 4; ++i)
#pragma unroll
            for (int j = 0; j < 4; ++j)
                acc[i][j] = MFMA16(af[i], bfr[j], acc[i][j]);
        buf ^= 1;
    }
#pragma unroll
    for (int i = 0; i < 4; ++i)
#pragma unroll
        for (int j = 0; j < 4; ++j) {
            const int c = bn + wn + j * 16 + l15;
#pragma unroll
            for (int rg = 0; rg < 4; ++rg) {
                const int m = bm + wm + i * 16 + l16 * 4 + rg;
                g.C[(size_t)m * 1024 + c] = f2bf(acc[i][j][rg]);
            }
        }
}

// ---------------- prep2: combine split-K partials into keff/cc, vT, qh ----------------
__global__ __launch_bounds__(256) void prep2(
    const u16* pk0, const u16* pk1, const u16* pr0, const u16* pr1,
    const u16* pv0, const u16* pv1, const u16* pq0, const u16* pq1,
    const float* kbi, const float* vbi, const float* rwb, const float* rrb,
    const int* mask, u16* keff, float* cc, u16* vT, u16* qhb)
{
    __shared__ float tb[32][33];
    const int bid = blockIdx.x, tid = threadIdx.x;
    if (bid < 2048) {
        const int t = bid * 256 + tid;
        const int row = t >> 4, li = t & 15;
        const int n = (row >> 10) & 15, kk = row & 1023, b = row >> 14;
        const size_t mi = ((size_t)(b * 1024 + kk)) * 1024 + n * 64 + li * 4;
        const size_t pi = ((size_t)kk) * 1024 + n * 64 + li * 4;
        const float4 k0v = unp4(*(const uint2*)&pk0[mi]);
        const float4 k1v = unp4(*(const uint2*)&pk1[mi]);
        const float4 r0v = unp4(*(const uint2*)&pr0[pi]);
        const float4 r1v = unp4(*(const uint2*)&pr1[pi]);
        const float4 kb4 = *(const float4*)&kbi[n * 64 + li * 4];
        float4 kv, rv;
        kv.x = k0v.x + k1v.x + kb4.x; kv.y = k0v.y + k1v.y + kb4.y;
        kv.z = k0v.z + k1v.z + kb4.z; kv.w = k0v.w + k1v.w + kb4.w;
        rv.x = r0v.x + r1v.x; rv.y = r0v.y + r1v.y;
        rv.z = r0v.z + r1v.z; rv.w = r0v.w + r1v.w;
        const float4 w1 = *(const float4*)&rwb[n * 64 + li * 4];
        const float4 w2 = *(const float4*)&rrb[n * 64 + li * 4];
        float s = w1.x * kv.x + w1.y * kv.y + w1.z * kv.z + w1.w * kv.w
                + w2.x * rv.x + w2.y * rv.y + w2.z * rv.z + w2.w * rv.w;
        uint2 o;
        o.x = (u32)f2bf(kv.x + rv.x) | ((u32)f2bf(kv.y + rv.y) << 16);
        o.y = (u32)f2bf(kv.z + rv.z) | ((u32)f2bf(kv.w + rv.w) << 16);
        *(uint2*)&keff[(size_t)row * 64 + li * 4] = o;
#pragma unroll
        for (int m = 1; m < 16; m <<= 1) s += __shfl_xor(s, m);
        if (li == 0)
            cc[row] = LOG2E * (NORMSC * s - BIGC * (float)mask[b * 1024 + kk]);
        return;
    }
    if (bid < 4096) {
        const int t = bid - 2048;
        const int head = t >> 6, tt = t & 63;
        const int b = head >> 4, n = head & 15;
        const int r0 = (tt >> 1) * 32, c0 = (tt & 1) * 32;
        const int tx = tid & 31, ty = tid >> 5;
        const float vb = vbi[n * 64 + c0 + tx];
        for (int i = ty; i < 32; i += 8) {
            const size_t idx = ((size_t)(b * 1024 + r0 + i)) * 1024 + n * 64 + c0 + tx;
            tb[i][tx] = bf2f(pv0[idx]) + bf2f(pv1[idx]) + vb;
        }
        __syncthreads();
        u16* out = vT + (size_t)head * 65536;
        for (int i = ty; i < 32; i += 8)
            out[(size_t)(c0 + i) * 1024 + r0 + tx] = f2bf(tb[tx][i]);
        return;
    }
    const int t = bid - 4096;
    const int e = t * 1024 + tid * 4;
    const int m = e >> 10, c = e & 1023;
    const float4 a = unp4(*(const uint2*)&pq0[e]);
    const float4 b4 = unp4(*(const uint2*)&pq1[e]);
    uint2 o;
    o.x = (u32)f2bf(a.x + b4.x) | ((u32)f2bf(a.y + b4.y) << 16);
    o.y = (u32)f2bf(a.z + b4.z) | ((u32)f2bf(a.w + b4.w) << 16);
    const int b2 = m >> 10, l = m & 1023, n = c >> 6, h = c & 63;
    *(uint2*)&qhb[(((size_t)(b2 * NHEAD + n)) * 1024 + l) * 64 + h] = o;
}

// ---------------- MFMA flash attention, XCD-affine, double-buffered staging ----------------
// 1024 blocks x 128 threads: XCD c hosts heads 4c..4c+3 (KV 1MB L2-resident).
// Rotation-swizzled LDS (mod 8); no online max (scores bounded; masked -> exp2(-1.44e6)=0).
__global__ __launch_bounds__(128) void attn_mfma(
    const u16* qb, const u16* kb, const u16* vtb, const float* ccomb, u16* O)
{
    __shared__ u16   Ks[2][4096];   // 2 x (64 keys x 64 h rotated) 16KB
    __shared__ u16   Vs[2][4096];   // 2 x (64 h x 64 keys rotated) 16KB
    __shared__ __bf16 Ps[2][1024];  // per-wave 16x64 P rotated, 4KB
    const int tid = threadIdx.x;
    const int w = tid >> 6, lane = tid & 63;
    const int l15 = lane & 15, l16 = lane >> 4;
    const int bid = blockIdx.x;
    const int i128 = bid >> 3;
    const int head = (bid & 7) * 4 + (i128 >> 5);   // 4 heads per XCD
    const int q0 = (i128 & 31) * 32;
    const int b = head >> 4, n = head & 15;
    const size_t hoff = (size_t)head * 65536;
    const u16* qh = qb + hoff;
    const char* khc = (const char*)(kb + hoff);
    const char* vtc = (const char*)(vtb + hoff);
    const float* cc = ccomb + head * 1024;
    __bf16* Pw = Ps[w];

    bf16x8 qf[2];
    {
        const size_t rb = ((size_t)(q0 + w * 16 + l15)) * 64 + l16 * 8;
        qf[0] = *(const bf16x8*)&qh[rb];
        qf[1] = *(const bf16x8*)&qh[rb + 32];
    }
    f32x4 Oacc[4] = {};
    float lsum[4] = {};

    const int sr0 = w * 32 + (lane >> 3);
    const int sc0 = lane & 7;
#pragma unroll
    for (int i = 0; i < 4; ++i) {
        const int r = sr0 + i * 8;
        async16(khc + r * 128 + (((sc0 + r) & 7) << 4), (char*)Ks[0] + r * 128 + sc0 * 16);
        async16(vtc + (size_t)r * 2048 + (((sc0 + r) & 7) << 4), (char*)Vs[0] + r * 128 + sc0 * 16);
    }
    int buf = 0;
    for (int kc = 0; kc < 16; ++kc) {
        __syncthreads();  // buf's loads drained; all waves done reading buf^1
        if (kc < 15) {    // prefetch next chunk into buf^1
            const int kn = kc + 1;
#pragma unroll
            for (int i = 0; i < 4; ++i) {
                const int r = sr0 + i * 8;
                async16(khc + kn * 8192 + r * 128 + (((sc0 + r) & 7) << 4),
                        (char*)Ks[buf ^ 1] + r * 128 + sc0 * 16);
                async16(vtc + (size_t)r * 2048 + kn * 128 + (((sc0 + r) & 7) << 4),
                        (char*)Vs[buf ^ 1] + r * 128 + sc0 * 16);
            }
        }
        const u16* Kb = Ks[buf];
        const u16* Vb = Vs[buf];
        f32x4 sc[4];
#pragma unroll
        for (int j = 0; j < 4; ++j) {
            const int rk2 = j * 16 + l15;
            const int base = rk2 * 64;
            f32x4 a = {0.f, 0.f, 0.f, 0.f};
            a = MFMA16(qf[0], *(const bf16x8*)&Kb[base + (((l16 - rk2) & 7) << 3)], a);
            a = MFMA16(qf[1], *(const bf16x8*)&Kb[base + (((l16 + 4 - rk2) & 7) << 3)], a);
            const float cadd = cc[kc * 64 + j * 16 + l15];
            sc[j] = a * SC2 + cadd;
        }
#pragma unroll
        for (int j = 0; j < 4; ++j) {
            const int cg = j * 2 + (l15 >> 3);
#pragma unroll
            for (int rg = 0; rg < 4; ++rg) {
                const float p = exp2f(sc[j][rg]);
                lsum[rg] += p;
                const int row = l16 * 4 + rg;
                Pw[row * 64 + (((cg - row) & 7) << 3) + (l15 & 7)] = (__bf16)p;
            }
        }
        bf16x8 pf[2];
#pragma unroll
        for (int f = 0; f < 2; ++f)
            pf[f] = *(const bf16x8*)&Pw[l15 * 64 + (((f * 4 + l16 - l15) & 7) << 3)];
#pragma unroll
        for (int t4 = 0; t4 < 4; ++t4) {
#pragma unroll
            for (int f = 0; f < 2; ++f) {
                const int vr = t4 * 16 + l15;
                const int ch = f * 4 + l16;
                const bf16x8 vf = *(const bf16x8*)&Vb[vr * 64 + (((ch - vr) & 7) << 3)];
                Oacc[t4] = MFMA16(pf[f], vf, Oacc[t4]);
            }
        }
        buf ^= 1;
    }
    float inv[4];
#pragma unroll
    for (int rg = 0; rg < 4; ++rg) {
        float s = lsum[rg];
#pragma unroll
        for (int m = 1; m < 16; m <<= 1) s += __shfl_xor(s, m);
        inv[rg] = 1.0f / s;
    }
#pragma unroll
    for (int t4 = 0; t4 < 4; ++t4) {
#pragma unroll
        for (int rg = 0; rg < 4; ++rg) {
            const int srow = q0 + w * 16 + l16 * 4 + rg;
            const int col = n * 64 + t4 * 16 + l15;
            O[((size_t)b * 1024 + srow) * 1024 + col] = f2bf(Oacc[t4][rg] * inv[rg]);
        }
    }
}

// ---------------- layernorm: out = LN(po0+po1+po2+po3 + post_b + resid) ----------------
__global__ __launch_bounds__(256) void ln_kernel(
    const u16* __restrict__ p0, const u16* __restrict__ p1,
    const u16* __restrict__ p2, const u16* __restrict__ p3,
    const float* __restrict__ resid, const float* __restrict__ pb,
    const float* __restrict__ g, const float* __restrict__ bb,
    float* __restrict__ out)
{
    const int row = blockIdx.x;
    const int tid = threadIdx.x;
    const size_t i = (size_t)row * DMODEL + tid * 4;
    const float4 a0 = unp4(*(const uint2*)&p0[i]);
    const float4 a1 = unp4(*(const uint2*)&p1[i]);
    const float4 a2 = unp4(*(const uint2*)&p2[i]);
    const float4 a3 = unp4(*(const uint2*)&p3[i]);
    const float4 rr = *(const float4*)&resid[i];
    const float4 pv = *(const float4*)&pb[tid * 4];
    float4 v;
    v.x = a0.x + a1.x + a2.x + a3.x + rr.x + pv.x;
    v.y = a0.y + a1.y + a2.y + a3.y + rr.y + pv.y;
    v.z = a0.z + a1.z + a2.z + a3.z + rr.z + pv.z;
    v.w = a0.w + a1.w + a2.w + a3.w + rr.w + pv.w;
    float s1 = v.x + v.y + v.z + v.w;
    float s2 = v.x * v.x + v.y * v.y + v.z * v.z + v.w * v.w;
#pragma unroll
    for (int off = 32; off; off >>= 1) {
        s1 += __shfl_down(s1, off);
        s2 += __shfl_down(s2, off);
    }
    __shared__ float rb[8];
    if ((tid & 63) == 0) { rb[tid >> 6] = s1; rb[4 + (tid >> 6)] = s2; }
    __syncthreads();
    if (tid == 0) {
        rb[0] = rb[0] + rb[1] + rb[2] + rb[3];
        rb[4] = rb[4] + rb[5] + rb[6] + rb[7];
    }
    __syncthreads();
    s1 = rb[0]; s2 = rb[4];
    const float mu = s1 * (1.0f / DMODEL);
    const float var = s2 * (1.0f / DMODEL) - mu * mu;
    const float rstd = rsqrtf(var + 1e-5f);
    const float4 gv = *(const float4*)&g[tid * 4];
    const float4 bv = *(const float4*)&bb[tid * 4];
    float4 o;
    o.x = (v.x - mu) * rstd * gv.x + bv.x;
    o.y = (v.y - mu) * rstd * gv.y + bv.y;
    o.z = (v.z - mu) * rstd * gv.z + bv.z;
    o.w = (v.w - mu) * rstd * gv.w + bv.w;
    *(float4*)&out[i] = o;
}

extern "C" void kernel_launch(void* const* d_in, const int* in_sizes, int n_in,
                              void* d_out, int out_size, void* d_ws, size_t ws_size,
                              hipStream_t stream)
{
    (void)in_sizes; (void)n_in; (void)out_size; (void)ws_size;
    const float* q   = (const float*)d_in[0];
    const float* k   = (const float*)d_in[1];
    const float* v   = (const float*)d_in[2];
    const float* pos = (const float*)d_in[3];
    const int*   msk = (const int*)d_in[4];
    const float* qw  = (const float*)d_in[5];
    const float* kw  = (const float*)d_in[6];
    const float* kbi = (const float*)d_in[7];
    const float* vw  = (const float*)d_in[8];
    const float* vbi = (const float*)d_in[9];
    const float* rwb = (const float*)d_in[10];
    const float* rrb = (const float*)d_in[11];
    const float* rk  = (const float*)d_in[12];
    const float* pw  = (const float*)d_in[13];
    const float* pb  = (const float*)d_in[14];
    const float* lg  = (const float*)d_in[15];
    const float* lb  = (const float*)d_in[16];
    float* out = (float*)d_out;

    // ---- workspace layout (~81 MB) ----
    float* fb = (float*)d_ws;
    float* cc   = fb;                 // 32K f
    u16* us   = (u16*)(cc + 32768);
    u16* qbf  = us;                   // 2M u16 (reused as Obf)
    u16* kbf  = qbf + 2097152;
    u16* vbf  = kbf + 2097152;
    u16* posb = vbf + 2097152;        // 1M
    u16* qwT  = posb + 1048576;       // 1M
    u16* kwT  = qwT + 1048576;
    u16* vwT  = kwT + 1048576;
    u16* pwT  = vwT + 1048576;
    u16* WrT  = pwT + 1048576;
    u16* qhb  = WrT + 1048576;        // 2M
    u16* keffb= qhb + 2097152;        // 2M
    u16* vTb  = keffb + 2097152;      // 2M
    u16* pq0  = vTb + 2097152;        // 2M x6 (q/k/v partials)
    u16* pq1  = pq0 + 2097152;
    u16* pk0  = pq1 + 2097152;
    u16* pk1  = pk0 + 2097152;
    u16* pv0  = pk1 + 2097152;
    u16* pv1  = pv0 + 2097152;
    u16* pr0  = pv1 + 2097152;        // 1M x2 (pos partials)
    u16* pr1  = pr0 + 1048576;
    u16* po0  = pr1 + 1048576;        // 2M x4 (post partials)
    u16* po1  = po0 + 2097152;
    u16* po2  = po1 + 2097152;
    u16* po3  = po2 + 2097152;
    u16* Obf  = qbf;

    dim3 blk(256);
    prep_all<<<12288, blk, 0, stream>>>(q, k, v, pos, qw, kw, vw, pw, rk,
                                        qbf, kbf, vbf, posb, qwT, kwT, vwT, pwT, WrT);

    GJ jq0 = {qbf,  qwT, pq0, 2048, 0,   512};
    GJ jq1 = {qbf,  qwT, pq1, 2048, 512, 512};
    GJ jk0 = {kbf,  kwT, pk0, 2048, 0,   512};
    GJ jk1 = {kbf,  kwT, pk1, 2048, 512, 512};
    GJ jv0 = {vbf,  vwT, pv0, 2048, 0,   512};
    GJ jv1 = {vbf,  vwT, pv1, 2048, 512, 512};
    GJ jp0 = {posb, WrT, pr0, 1024, 0,   512};
    GJ jp1 = {posb, WrT, pr1, 1024, 512, 512};
    gemm_p<<<1024, blk, 0, stream>>>(jq0, jq1, jk0, jk1, jv0, jv1, jp0, jp1, 8);

    prep2<<<6144, blk, 0, stream>>>(pk0, pk1, pr0, pr1, pv0, pv1, pq0, pq1,
                                    kbi, vbi, rwb, rrb, msk, keffb, cc, vTb, qhb);

    attn_mfma<<<1024, dim3(128), 0, stream>>>(qhb, keffb, vTb, cc, Obf);

    GJ jo0 = {Obf, pwT, po0, 2048, 0,   256};
    GJ jo1 = {Obf, pwT, po1, 2048, 256, 256};
    GJ jo2 = {Obf, pwT, po2, 2048, 512, 256};
    GJ jo3 = {Obf, pwT, po3, 2048, 768, 256};
    gemm_p<<<512, blk, 0, stream>>>(jo0, jo1, jo2, jo3, jo0, jo0, jo0, jo0, 4);

    ln_kernel<<<2048, blk, 0, stream>>>(po0, po1, po2, po3, q, pb, lg, lb, out);
}